// Round 1
// 49028.259 us; speedup vs baseline: 1.2197x; 1.2197x over previous
//
#include <hip/hip_runtime.h>
#include <hip/hip_fp16.h>

#define NB     64
#define TMEL   1000
#define TE     400
#define ENC    512
#define MELD   80
#define P1     128
#define P2     64
#define HID    256
#define KCOMB  832    // 64 + 512 + 256

// ---------------- ws byte offsets ----------------
#define OFF_ENCH  0u                  // half[64*400*512]          = 26,214,400 B
#define OFF_XH    26214400u           // half[64*1000*64]          =  8,192,000 B
#define OFF_WCH   34406400u           // half[4][832][256]         =  1,703,936 B
#define OFF_WQS   36110336u           // half[4][64][512]          =    262,144 B
#define OFF_WOS   36372480u           // half[4][64][80]           =     40,960 B
#define OFF_BSQ   36413440u           // float[4][256]             =      4,096 B
#define OFF_WP1T  36417536u           // float[80*128]             =     40,960 B
#define OFF_WP2T  36458496u           // float[128*64]             =     32,768 B
#define OFF_COMM  36491264u           // 64 groups * 20480 B       =  1,310,720 B
#define OFF_BAR   37801984u           // int[64*64]                =     16,384 B
// comm per-group layout (bytes): qp[4][512]f32 @0, ctxp[4][512]f32 @8192,
// ml[4][2]f32 @16384 (pad->16512), hq[2][256]f32 @16512, melp[4][80]f32 @18560

#define SEG1 13107200   // encH elems
#define SEG2 851968     // WcH
#define SEG3 131072     // WQS
#define SEG4 20480      // WOS
#define SEG5 1024       // BSQ
#define SEG6 10240      // WP1T
#define SEG7 8192       // WP2T
#define SEG8 4096       // bar ints
#define PREP_TOT (SEG1+SEG2+SEG3+SEG4+SEG5+SEG6+SEG7+SEG8)

// ---------------- dynamic LDS layout (decoder) ----------------
#define L_ENC   0u         // half[100*512]  = 102,400 B (my te-slice, loaded once)
#define L_WOS   102400u    // half[64*80]    =  10,240 B (my W_out k-slice)
#define L_SCR   112640u    // float[16*512]  =  32,768 B
#define L_Q     145408u    // float[512]
#define L_LIN   147456u    // float[832]
#define L_EN    150784u    // float[128]
#define L_GATE  151296u    // float[256]
#define L_H     152320u    // float[64]
#define L_C     152576u    // float[64]
#define L_RED   152832u    // float[16]
#define SMEM_BYTES 152896

__device__ __forceinline__ float fast_tanh(float x) {
    float e = __expf(2.f * x);
    return 1.f - 2.f * __builtin_amdgcn_rcpf(e + 1.f);
}
__device__ __forceinline__ float fast_sigmoid(float x) {
    return __builtin_amdgcn_rcpf(1.f + __expf(-x));
}

// ---- fence-free cross-block comm: relaxed agent-scope word ops.
__device__ __forceinline__ float gload(const float* p) {
    return __hip_atomic_load(p, __ATOMIC_RELAXED, __HIP_MEMORY_SCOPE_AGENT);
}
__device__ __forceinline__ void gstore(float* p, float v) {
    __hip_atomic_store(p, v, __ATOMIC_RELAXED, __HIP_MEMORY_SCOPE_AGENT);
}

// ---------------- prep: fp16 conversions + layouts + zero barriers ----------------
__global__ void prep_kernel(const float* __restrict__ enc,
                            const float* __restrict__ Wq,
                            const float* __restrict__ Wih,
                            const float* __restrict__ Whh,
                            const float* __restrict__ Wout,
                            const float* __restrict__ Wp1,
                            const float* __restrict__ Wp2,
                            const float* __restrict__ bih,
                            const float* __restrict__ bhh,
                            char* __restrict__ wsb) {
    long i = (long)blockIdx.x * blockDim.x + threadIdx.x;
    if (i >= PREP_TOT) return;
    if (i < SEG1) {                       // encH flat copy
        ((__half*)(wsb + OFF_ENCH))[i] = __float2half(enc[i]);
        return;
    }
    i -= SEG1;
    if (i < SEG2) {                       // WcH[m][k][jj]
        int m  = (int)(i / (KCOMB * 256));
        int rr = (int)(i % (KCOMB * 256));
        int k  = rr / 256, jj = rr % 256;
        int gate = jj >> 6, u = jj & 63;
        int jg = gate * 256 + m * 64 + u;
        float v = (k < 576) ? Wih[(size_t)jg * 576 + k] : Whh[(size_t)jg * 256 + (k - 576)];
        ((__half*)(wsb + OFF_WCH))[i] = __float2half(v);
        return;
    }
    i -= SEG2;
    if (i < SEG3) {                       // WQS[m][kk][j] = Wq[j*256 + 64m+kk]
        int m = (int)(i / (64 * 512));
        int rr = (int)(i % (64 * 512));
        int kk = rr / 512, j = rr % 512;
        ((__half*)(wsb + OFF_WQS))[i] = __float2half(Wq[(size_t)j * 256 + m * 64 + kk]);
        return;
    }
    i -= SEG3;
    if (i < SEG4) {                       // WOS[m][kk][jo] = Wout[jo*256 + 64m+kk]
        int m = (int)(i / (64 * 80));
        int rr = (int)(i % (64 * 80));
        int kk = rr / 80, jo = rr % 80;
        ((__half*)(wsb + OFF_WOS))[i] = __float2half(Wout[(size_t)jo * 256 + m * 64 + kk]);
        return;
    }
    i -= SEG4;
    if (i < SEG5) {                       // BSQ[m][jj]
        int m = (int)(i / 256), jj = (int)(i % 256);
        int gate = jj >> 6, u = jj & 63;
        int jg = gate * 256 + m * 64 + u;
        ((float*)(wsb + OFF_BSQ))[i] = bih[jg] + bhh[jg];
        return;
    }
    i -= SEG5;
    if (i < SEG6) {                       // wp1T[k*128+j] = Wp1[j*80+k]
        int j = (int)(i & 127), k = (int)(i >> 7);
        ((float*)(wsb + OFF_WP1T))[i] = Wp1[j * 80 + k];
        return;
    }
    i -= SEG6;
    if (i < SEG7) {                       // wp2T[k*64+j] = Wp2[j*128+k]
        int j = (int)(i & 63), k = (int)(i >> 6);
        ((float*)(wsb + OFF_WP2T))[i] = Wp2[j * 128 + k];
        return;
    }
    i -= SEG7;
    ((int*)(wsb + OFF_BAR))[i] = 0;       // zero barrier counters
}

// ---------------- prenet -> xH fp16 ----------------
__global__ __launch_bounds__(128) void prenet_kernel(const float* __restrict__ mel,
                                                     const float* __restrict__ bp1,
                                                     const float* __restrict__ bp2,
                                                     char* __restrict__ wsb) {
    __shared__ float mel_sh[MELD];
    __shared__ float hid_sh[P1];
    const float* wp1T = (const float*)(wsb + OFF_WP1T);
    const float* wp2T = (const float*)(wsb + OFF_WP2T);
    __half* xH = (__half*)(wsb + OFF_XH);
    int bt = blockIdx.x;
    int tid = threadIdx.x;
    if (tid < MELD) mel_sh[tid] = mel[(size_t)bt * MELD + tid];
    __syncthreads();
    {
        float acc = bp1[tid];
        #pragma unroll 4
        for (int k = 0; k < MELD; ++k) acc += mel_sh[k] * wp1T[k * P1 + tid];
        hid_sh[tid] = fmaxf(acc, 0.f);
    }
    __syncthreads();
    if (tid < P2) {
        float acc = bp2[tid];
        #pragma unroll 4
        for (int k = 0; k < P1; ++k) acc += hid_sh[k] * wp2T[k * P2 + tid];
        xH[(size_t)bt * P2 + tid] = __float2half(fmaxf(acc, 0.f));
    }
}

// ---------------- 4-block group barrier, FENCE-FREE ----------------
__device__ __forceinline__ void groupbar(int* c, int n) {
    __syncthreads();
    if (threadIdx.x == 0) {
        __hip_atomic_fetch_add(c, 1, __ATOMIC_RELAXED, __HIP_MEMORY_SCOPE_AGENT);
        while (__hip_atomic_load(c, __ATOMIC_RELAXED, __HIP_MEMORY_SCOPE_AGENT) < 4 * n)
            __builtin_amdgcn_s_sleep(1);
    }
    __syncthreads();
}

// ---------------- decoder: 256 blocks, 4 per batch; enc slice in LDS ----------------
__global__ __launch_bounds__(1024, 1) void decoder_kernel(const float* __restrict__ bq,
                                                          const float* __restrict__ we,
                                                          const float* __restrict__ bout,
                                                          char* __restrict__ wsb,
                                                          float* __restrict__ out) {
    extern __shared__ __align__(16) char smem[];
    __half* encL     = (__half*)(smem + L_ENC);
    __half* wosL     = (__half*)(smem + L_WOS);
    float*  scr      = (float*)(smem + L_SCR);
    float*  q_sh     = (float*)(smem + L_Q);
    float*  lin_sh   = (float*)(smem + L_LIN);
    float*  en_sh    = (float*)(smem + L_EN);
    float*  gates_sh = (float*)(smem + L_GATE);
    float*  h_sh     = (float*)(smem + L_H);
    float*  c_sh     = (float*)(smem + L_C);
    float*  red_sh   = (float*)(smem + L_RED);

    const int bid  = blockIdx.x;
    const int g    = bid & 63;      // batch / group
    const int m    = bid >> 6;      // member 0..3
    const int tid  = threadIdx.x;
    const int lane = tid & 63;
    const int wv   = tid >> 6;

    const __half* encH = (const __half*)(wsb + OFF_ENCH) + (size_t)g * TE * ENC + (size_t)m * 100 * ENC;
    const __half* xH   = (const __half*)(wsb + OFF_XH) + (size_t)g * TMEL * P2;
    const __half* wc   = (const __half*)(wsb + OFF_WCH) + (size_t)m * KCOMB * 256;
    const __half* wqs  = (const __half*)(wsb + OFF_WQS) + (size_t)m * 64 * 512;
    const __half* wos  = (const __half*)(wsb + OFF_WOS) + (size_t)m * 64 * 80;
    const float*  bsq  = (const float*)(wsb + OFF_BSQ) + m * 256;
    char*  comm = wsb + OFF_COMM + (size_t)g * 20480;
    float* qp   = (float*)(comm);            // [4][512]
    float* ctxp = (float*)(comm + 8192);     // [4][512]
    float* ml   = (float*)(comm + 16384);    // [4][2]
    float* hq   = (float*)(comm + 16512);    // [2][256]
    float* melp = (float*)(comm + 18560);    // [4][80]
    int*   barc = (int*)(wsb + OFF_BAR) + g * 64;
    float* outB = out + (size_t)g * TMEL * MELD;

    // ---- one-time LDS staging: enc slice (100 KB) + wos slice (10 KB)
    {
        const int4* s1 = (const int4*)encH;   // 6400 int4
        int4* d1 = (int4*)encL;
        for (int i = tid; i < 6400; i += 1024) d1[i] = s1[i];
        const int4* s2 = (const int4*)wos;    // 640 int4
        int4* d2 = (int4*)wosL;
        if (tid < 640) d2[tid] = s2[tid];
    }

    // ---- init: zero my comm slots (write-through!) + local state
    if (tid < 512) gstore(&qp[m * 512 + tid], 0.f);
    if (tid < 64) {
        gstore(&hq[m * 64 + tid], 0.f);
        gstore(&hq[256 + m * 64 + tid], 0.f);
        h_sh[tid] = 0.f;
        c_sh[tid] = 0.f;
    }
    groupbar(barc, 1);

    // per-lane energy constants: we2 = 2*we for my 8 columns, wsum = sum(we)
    float4 wa = ((const float4*)we)[lane * 2];
    float4 wb = ((const float4*)we)[lane * 2 + 1];
    float wsum = wa.x + wa.y + wa.z + wa.w + wb.x + wb.y + wb.z + wb.w;
    wa.x *= 2.f; wa.y *= 2.f; wa.z *= 2.f; wa.w *= 2.f;
    wb.x *= 2.f; wb.y *= 2.f; wb.z *= 2.f; wb.w *= 2.f;
    const float C2 = 2.8853900817779268f;   // 2*log2(e)

    const float* wq2 = (const float*)wqs;   // row kk = 256 floats (512 halves)

    for (int t = 0; t < TMEL; ++t) {
        // ================= phase A =================
        if (m == 0 && t > 0 && tid < MELD) {
            float o = bout[tid] + gload(&melp[tid]) + gload(&melp[80 + tid]) +
                      gload(&melp[160 + tid]) + gload(&melp[240 + tid]);
            outB[(size_t)(t - 1) * MELD + tid] = o;
        }
        if (tid < ENC)
            q_sh[tid] = bq[tid] + gload(&qp[tid]) + gload(&qp[512 + tid]) +
                        gload(&qp[1024 + tid]) + gload(&qp[1536 + tid]);
        __syncthreads();

        // energy for my 100 te rows (enc from LDS) — depth-2 row rotation so the
        // next row's ds_read_b128 is in flight during this row's ETERM chain.
        {
            float4 qa = ((const float4*)q_sh)[lane * 2];
            float4 qb = ((const float4*)q_sh)[lane * 2 + 1];
            int r = wv;
            float4 raw = ((const float4*)(encL + (size_t)r * ENC))[lane];
            while (r < 100) {
                int rn = r + 16;
                int rc = (rn < 100) ? rn : 0;
                float4 rawn = ((const float4*)(encL + (size_t)rc * ENC))[lane];
                const __half2* hp = (const __half2*)&raw;
                float p = wsum;
                float2 e;
                #define ETERM(qv, w2v, ev) { float a_ = (qv) + (ev); \
                    float x_ = exp2f(a_ * C2); \
                    float r_ = __builtin_amdgcn_rcpf(x_ + 1.f); \
                    p = fmaf(-(w2v), r_, p); }
                e = __half22float2(hp[0]); ETERM(qa.x, wa.x, e.x); ETERM(qa.y, wa.y, e.y);
                e = __half22float2(hp[1]); ETERM(qa.z, wa.z, e.x); ETERM(qa.w, wa.w, e.y);
                e = __half22float2(hp[2]); ETERM(qb.x, wb.x, e.x); ETERM(qb.y, wb.y, e.y);
                e = __half22float2(hp[3]); ETERM(qb.z, wb.z, e.x); ETERM(qb.w, wb.w, e.y);
                #undef ETERM
                #pragma unroll
                for (int off = 32; off; off >>= 1) p += __shfl_xor(p, off, 64);
                if (lane == 0) en_sh[r] = p;
                raw = rawn; r = rn;
            }
        }
        __syncthreads();
        if (wv == 0) {   // local max over 100
            float mx = (lane < 100) ? en_sh[lane] : -1e30f;
            if (lane < 36) mx = fmaxf(mx, en_sh[64 + lane]);
            #pragma unroll
            for (int off = 32; off; off >>= 1) mx = fmaxf(mx, __shfl_xor(mx, off, 64));
            if (lane == 0) red_sh[0] = mx;
        }
        __syncthreads();
        if (tid < 100) en_sh[tid] = __expf(en_sh[tid] - red_sh[0]);
        __syncthreads();
        if (wv == 0) {   // local sum
            float s = (lane < 100) ? en_sh[lane] : 0.f;
            if (lane < 36) s += en_sh[64 + lane];
            #pragma unroll
            for (int off = 32; off; off >>= 1) s += __shfl_xor(s, off, 64);
            if (lane == 0) red_sh[1] = s;
        }
        // ctx partial (unnormalized, local-max scaled; enc from LDS) — depth-2 rotation
        {
            float4 a0 = {0.f, 0.f, 0.f, 0.f}, a1 = {0.f, 0.f, 0.f, 0.f};
            int r = wv;
            float4 raw = ((const float4*)(encL + (size_t)r * ENC))[lane];
            while (r < 100) {
                int rn = r + 16;
                int rc = (rn < 100) ? rn : 0;
                float4 rawn = ((const float4*)(encL + (size_t)rc * ENC))[lane];
                float ex = en_sh[r];
                const __half2* hp = (const __half2*)&raw;
                float2 e;
                e = __half22float2(hp[0]); a0.x = fmaf(ex, e.x, a0.x); a0.y = fmaf(ex, e.y, a0.y);
                e = __half22float2(hp[1]); a0.z = fmaf(ex, e.x, a0.z); a0.w = fmaf(ex, e.y, a0.w);
                e = __half22float2(hp[2]); a1.x = fmaf(ex, e.x, a1.x); a1.y = fmaf(ex, e.y, a1.y);
                e = __half22float2(hp[3]); a1.z = fmaf(ex, e.x, a1.z); a1.w = fmaf(ex, e.y, a1.w);
                raw = rawn; r = rn;
            }
            ((float4*)(scr + wv * 512))[lane * 2] = a0;
            ((float4*)(scr + wv * 512))[lane * 2 + 1] = a1;
        }
        __syncthreads();
        if (tid < ENC) {
            float c = 0.f;
            #pragma unroll
            for (int w = 0; w < 16; ++w) c += scr[w * 512 + tid];
            gstore(&ctxp[m * 512 + tid], c);
        }
        if (tid == 0) { gstore(&ml[m * 2], red_sh[0]); gstore(&ml[m * 2 + 1], red_sh[1]); }

        // ---- prefetch my gates-weight k-chunk groups 0..3 BEFORE the barrier:
        // these are step-invariant L2 reads, so their latency hides under the
        // barrier spin + phase-B comm round trip.
        const int kb = wv * 52;
        const float2* wp = (const float2*)wc + (size_t)kb * 64 + lane;
        float2 wbuf[4][4];
        #pragma unroll
        for (int gg = 0; gg < 4; ++gg) {
            #pragma unroll
            for (int i = 0; i < 4; ++i) wbuf[gg][i] = wp[(size_t)(4 * gg + i) * 64];
        }

        groupbar(barc, 2 * t + 2);

        // ================= phase B =================
        // Issue ALL comm loads up front (ml, ctxp, hq, xH are independent) —
        // previously ml -> sync -> ctxp were two serialized LLC round trips.
        float c0, c1, c2, c3, xv, hv;
        if (tid < ENC) {
            c0 = gload(&ctxp[tid]);        c1 = gload(&ctxp[512 + tid]);
            c2 = gload(&ctxp[1024 + tid]); c3 = gload(&ctxp[1536 + tid]);
        }
        if (tid < P2) xv = __half2float(xH[(size_t)t * P2 + tid]);
        if (tid >= 512 && tid < 768) hv = gload(&hq[(t & 1) * 256 + (tid - 512)]);
        if (tid < 8) red_sh[4 + tid] = gload(&ml[tid]);
        __syncthreads();
        float M = fmaxf(fmaxf(red_sh[4], red_sh[6]), fmaxf(red_sh[8], red_sh[10]));
        float s0 = __expf(red_sh[4] - M), s1 = __expf(red_sh[6] - M);
        float s2 = __expf(red_sh[8] - M), s3 = __expf(red_sh[10] - M);
        float linv = __builtin_amdgcn_rcpf(s0 * red_sh[5] + s1 * red_sh[7] +
                                           s2 * red_sh[9] + s3 * red_sh[11]);
        if (tid < ENC) lin_sh[64 + tid] = (s0 * c0 + s1 * c1 + s2 * c2 + s3 * c3) * linv;
        if (tid < P2) lin_sh[tid] = xv;
        if (tid >= 512 && tid < 768) lin_sh[576 + (tid - 512)] = hv;
        __syncthreads();

        // gates quarter: 16 waves x 52-k chunks, 4 j per lane.
        // Distance-4 rotating buffer => 16 dwordx2 loads in flight, latency hidden.
        {
            float4 acc = {0.f, 0.f, 0.f, 0.f};
            #pragma unroll
            for (int gg = 0; gg < 13; ++gg) {
                float2 w0 = wbuf[gg & 3][0], w1 = wbuf[gg & 3][1];
                float2 w2 = wbuf[gg & 3][2], w3 = wbuf[gg & 3][3];
                if (gg + 4 < 13) {
                    #pragma unroll
                    for (int i = 0; i < 4; ++i)
                        wbuf[gg & 3][i] = wp[(size_t)(4 * (gg + 4) + i) * 64];
                }
                {
                    float s = lin_sh[kb + 4 * gg + 0];
                    const __half2* hp = (const __half2*)&w0;
                    float2 wA = __half22float2(hp[0]), wB = __half22float2(hp[1]);
                    acc.x = fmaf(s, wA.x, acc.x); acc.y = fmaf(s, wA.y, acc.y);
                    acc.z = fmaf(s, wB.x, acc.z); acc.w = fmaf(s, wB.y, acc.w);
                }
                {
                    float s = lin_sh[kb + 4 * gg + 1];
                    const __half2* hp = (const __half2*)&w1;
                    float2 wA = __half22float2(hp[0]), wB = __half22float2(hp[1]);
                    acc.x = fmaf(s, wA.x, acc.x); acc.y = fmaf(s, wA.y, acc.y);
                    acc.z = fmaf(s, wB.x, acc.z); acc.w = fmaf(s, wB.y, acc.w);
                }
                {
                    float s = lin_sh[kb + 4 * gg + 2];
                    const __half2* hp = (const __half2*)&w2;
                    float2 wA = __half22float2(hp[0]), wB = __half22float2(hp[1]);
                    acc.x = fmaf(s, wA.x, acc.x); acc.y = fmaf(s, wA.y, acc.y);
                    acc.z = fmaf(s, wB.x, acc.z); acc.w = fmaf(s, wB.y, acc.w);
                }
                {
                    float s = lin_sh[kb + 4 * gg + 3];
                    const __half2* hp = (const __half2*)&w3;
                    float2 wA = __half22float2(hp[0]), wB = __half22float2(hp[1]);
                    acc.x = fmaf(s, wA.x, acc.x); acc.y = fmaf(s, wA.y, acc.y);
                    acc.z = fmaf(s, wB.x, acc.z); acc.w = fmaf(s, wB.y, acc.w);
                }
            }
            ((float4*)(scr + wv * 256))[lane] = acc;
        }

        // ---- prefetch q-projection weights groups 0..1 (independent of gates
        // reduce / LSTM) so their latency hides under the next two phases.
        float qbuf[2][16];
        if (tid < 256) {
            #pragma unroll
            for (int gg = 0; gg < 2; ++gg) {
                #pragma unroll
                for (int i = 0; i < 16; ++i)
                    qbuf[gg][i] = wq2[(size_t)(16 * gg + i) * 256 + tid];
            }
        }
        __syncthreads();
        if (tid < 256) {
            float gsum = bsq[tid];
            #pragma unroll
            for (int w = 0; w < 16; ++w) gsum += scr[w * 256 + tid];
            gates_sh[tid] = gsum;
        }
        __syncthreads();
        if (tid < 64) {   // LSTM pointwise for my h chunk
            float ig = fast_sigmoid(gates_sh[tid]);
            float fg = fast_sigmoid(gates_sh[64 + tid]);
            float gg = fast_tanh(gates_sh[128 + tid]);
            float og = fast_sigmoid(gates_sh[192 + tid]);
            float cN = fmaf(fg, c_sh[tid], ig * gg);
            float hN = og * fast_tanh(cN);
            c_sh[tid] = cN; h_sh[tid] = hN;
            gstore(&hq[((t + 1) & 1) * 256 + m * 64 + tid], hN);
        }
        __syncthreads();
        // q k-partial: 256 threads x j-pairs, distance-2 rotating 16-wide buffer
        // (32 dword loads in flight).
        if (tid < 256) {
            float a0 = 0.f, a1 = 0.f;
            #pragma unroll
            for (int gg = 0; gg < 4; ++gg) {
                float rr[16];
                #pragma unroll
                for (int i = 0; i < 16; ++i) rr[i] = qbuf[gg & 1][i];
                if (gg + 2 < 4) {
                    #pragma unroll
                    for (int i = 0; i < 16; ++i)
                        qbuf[gg & 1][i] = wq2[(size_t)(16 * (gg + 2) + i) * 256 + tid];
                }
                #pragma unroll
                for (int i = 0; i < 16; ++i) {
                    __half2 hh = *(const __half2*)&rr[i];
                    float2 w = __half22float2(hh);
                    float h = h_sh[16 * gg + i];
                    a0 = fmaf(h, w.x, a0); a1 = fmaf(h, w.y, a1);
                }
            }
            gstore(&qp[m * 512 + 2 * tid], a0);
            gstore(&qp[m * 512 + 2 * tid + 1], a1);
        }
        // mel k-partial (wos from LDS) — unrolled so LDS reads pipeline
        if (tid >= 512 && tid < 512 + MELD) {
            int jo = tid - 512;
            float a = 0.f;
            #pragma unroll 8
            for (int kk = 0; kk < 64; ++kk) a = fmaf(h_sh[kk], __half2float(wosL[kk * 80 + jo]), a);
            gstore(&melp[m * 80 + jo], a);
        }
        groupbar(barc, 2 * t + 3);
    }
    // epilogue: last mel row
    if (m == 0 && tid < MELD) {
        float o = bout[tid] + gload(&melp[tid]) + gload(&melp[80 + tid]) +
                  gload(&melp[160 + tid]) + gload(&melp[240 + tid]);
        outB[(size_t)(TMEL - 1) * MELD + tid] = o;
    }
}

extern "C" void kernel_launch(void* const* d_in, const int* in_sizes, int n_in,
                              void* d_out, int out_size, void* d_ws, size_t ws_size,
                              hipStream_t stream) {
    (void)in_sizes; (void)n_in; (void)out_size; (void)ws_size;
    const float* mel  = (const float*)d_in[0];
    const float* enc  = (const float*)d_in[1];
    const float* Wp1  = (const float*)d_in[2];
    const float* bp1  = (const float*)d_in[3];
    const float* Wp2  = (const float*)d_in[4];
    const float* bp2  = (const float*)d_in[5];
    const float* Wq   = (const float*)d_in[6];
    const float* bq   = (const float*)d_in[7];
    const float* We   = (const float*)d_in[8];
    // d_in[9] = b_e : softmax-invariant constant -> unused
    const float* Wih  = (const float*)d_in[10];
    const float* Whh  = (const float*)d_in[11];
    const float* bih  = (const float*)d_in[12];
    const float* bhh  = (const float*)d_in[13];
    const float* Wout = (const float*)d_in[14];
    const float* bout = (const float*)d_in[15];
    char* wsb  = (char*)d_ws;
    float* out = (float*)d_out;

    long prepBlocks = (PREP_TOT + 255) / 256;
    prep_kernel<<<dim3((unsigned)prepBlocks), 256, 0, stream>>>(
        enc, Wq, Wih, Whh, Wout, Wp1, Wp2, bih, bhh, wsb);
    prenet_kernel<<<NB * TMEL, 128, 0, stream>>>(mel, bp1, bp2, wsb);

    hipFuncSetAttribute((const void*)decoder_kernel,
                        hipFuncAttributeMaxDynamicSharedMemorySize, SMEM_BYTES);

    const float* bq_a = bq; const float* we_a = We; const float* bo_a = bout;
    char* ws_a = wsb; float* out_a = out;
    void* args[] = { &bq_a, &we_a, &bo_a, &ws_a, &out_a };
    hipLaunchCooperativeKernel((const void*)decoder_kernel, dim3(256), dim3(1024),
                               args, SMEM_BYTES, stream);
}

// Round 4
// 44771.432 us; speedup vs baseline: 1.3357x; 1.0951x over previous
//
#include <hip/hip_runtime.h>
#include <hip/hip_fp16.h>

#define NB     64
#define TMEL   1000
#define TE     400
#define ENC    512
#define MELD   80
#define P1     128
#define P2     64
#define HID    256
#define KCOMB  832    // 64 + 512 + 256

#define C2F    2.8853900817779268f   // 2*log2(e), folded into encH & WQS at prep
#define INVC2F 0.34657359027997264f  // 1/C2F

// ---------------- ws byte offsets ----------------
#define OFF_ENCH  0u                  // half[64*400*512] (pre-scaled by C2)
#define OFF_XH    26214400u           // half[64*1000*64]
#define OFF_WCH   34406400u           // half[4][832][256]
#define OFF_WQS   36110336u           // half[4][64][512] (pre-scaled by C2)
#define OFF_WOS   36372480u           // half[4][64][80]
#define OFF_BSQ   36413440u           // float[4][256]
#define OFF_WP1T  36417536u           // float[80*128]
#define OFF_WP2T  36458496u           // float[128*64]
#define OFF_COMM  36491264u           // 64 groups * 20480 B
#define OFF_BAR   37801984u           // int[64*64]
// comm per-group layout (bytes): qp[4][512]f32 @0, ctxp[4][512]f32 @8192,
// ml[4][2]f32 @16384 (pad->16512), hq[2][256]f32 @16512, melp[4][80]f32 @18560

#define SEG1 13107200
#define SEG2 851968
#define SEG3 131072
#define SEG4 20480
#define SEG5 1024
#define SEG6 10240
#define SEG7 8192
#define SEG8 4096
#define PREP_TOT (SEG1+SEG2+SEG3+SEG4+SEG5+SEG6+SEG7+SEG8)

// ---------------- dynamic LDS layout (decoder) ----------------
#define L_ENC   0u         // half[100*512]  = 102,400 B
#define L_WOS   102400u    // half[64*80]    =  10,240 B
#define L_SCR   112640u    // float[16*512]  =  32,768 B
#define L_Q     145408u    // float[512]
#define L_LIN   147456u    // float[832]
#define L_EN    150784u    // float[128]
#define L_GATE  151296u    // float[256]
#define L_H     152320u    // float[64]
#define L_C     152576u    // float[64]
#define L_RED   152832u    // float[16]
#define SMEM_BYTES 152896

__device__ __forceinline__ float fast_tanh(float x) {
    float e = __expf(2.f * x);
    return 1.f - 2.f * __builtin_amdgcn_rcpf(e + 1.f);
}
__device__ __forceinline__ float fast_sigmoid(float x) {
    return __builtin_amdgcn_rcpf(1.f + __expf(-x));
}

// ---- cross-block comm: relaxed agent-scope word ops (proven-correct path).
__device__ __forceinline__ float gload(const float* p) {
    return __hip_atomic_load(p, __ATOMIC_RELAXED, __HIP_MEMORY_SCOPE_AGENT);
}
__device__ __forceinline__ void gstore(float* p, float v) {
    __hip_atomic_store(p, v, __ATOMIC_RELAXED, __HIP_MEMORY_SCOPE_AGENT);
}

// ---------------- prep ----------------
__global__ void prep_kernel(const float* __restrict__ enc,
                            const float* __restrict__ Wq,
                            const float* __restrict__ Wih,
                            const float* __restrict__ Whh,
                            const float* __restrict__ Wout,
                            const float* __restrict__ Wp1,
                            const float* __restrict__ Wp2,
                            const float* __restrict__ bih,
                            const float* __restrict__ bhh,
                            char* __restrict__ wsb) {
    long i = (long)blockIdx.x * blockDim.x + threadIdx.x;
    if (i >= PREP_TOT) return;
    if (i < SEG1) {                       // encH flat copy, pre-scaled by C2
        ((__half*)(wsb + OFF_ENCH))[i] = __float2half(enc[i] * C2F);
        return;
    }
    i -= SEG1;
    if (i < SEG2) {                       // WcH[m][k][jj]
        int m  = (int)(i / (KCOMB * 256));
        int rr = (int)(i % (KCOMB * 256));
        int k  = rr / 256, jj = rr % 256;
        int gate = jj >> 6, u = jj & 63;
        int jg = gate * 256 + m * 64 + u;
        float v = (k < 576) ? Wih[(size_t)jg * 576 + k] : Whh[(size_t)jg * 256 + (k - 576)];
        ((__half*)(wsb + OFF_WCH))[i] = __float2half(v);
        return;
    }
    i -= SEG2;
    if (i < SEG3) {                       // WQS[m][kk][j] pre-scaled by C2
        int m = (int)(i / (64 * 512));
        int rr = (int)(i % (64 * 512));
        int kk = rr / 512, j = rr % 512;
        ((__half*)(wsb + OFF_WQS))[i] = __float2half(Wq[(size_t)j * 256 + m * 64 + kk] * C2F);
        return;
    }
    i -= SEG3;
    if (i < SEG4) {                       // WOS[m][kk][jo]
        int m = (int)(i / (64 * 80));
        int rr = (int)(i % (64 * 80));
        int kk = rr / 80, jo = rr % 80;
        ((__half*)(wsb + OFF_WOS))[i] = __float2half(Wout[(size_t)jo * 256 + m * 64 + kk]);
        return;
    }
    i -= SEG4;
    if (i < SEG5) {                       // BSQ[m][jj]
        int m = (int)(i / 256), jj = (int)(i % 256);
        int gate = jj >> 6, u = jj & 63;
        int jg = gate * 256 + m * 64 + u;
        ((float*)(wsb + OFF_BSQ))[i] = bih[jg] + bhh[jg];
        return;
    }
    i -= SEG5;
    if (i < SEG6) {
        int j = (int)(i & 127), k = (int)(i >> 7);
        ((float*)(wsb + OFF_WP1T))[i] = Wp1[j * 80 + k];
        return;
    }
    i -= SEG6;
    if (i < SEG7) {
        int j = (int)(i & 63), k = (int)(i >> 6);
        ((float*)(wsb + OFF_WP2T))[i] = Wp2[j * 128 + k];
        return;
    }
    i -= SEG7;
    ((int*)(wsb + OFF_BAR))[i] = 0;
}

// ---------------- prenet -> xH fp16 ----------------
__global__ __launch_bounds__(128) void prenet_kernel(const float* __restrict__ mel,
                                                     const float* __restrict__ bp1,
                                                     const float* __restrict__ bp2,
                                                     char* __restrict__ wsb) {
    __shared__ float mel_sh[MELD];
    __shared__ float hid_sh[P1];
    const float* wp1T = (const float*)(wsb + OFF_WP1T);
    const float* wp2T = (const float*)(wsb + OFF_WP2T);
    __half* xH = (__half*)(wsb + OFF_XH);
    int bt = blockIdx.x;
    int tid = threadIdx.x;
    if (tid < MELD) mel_sh[tid] = mel[(size_t)bt * MELD + tid];
    __syncthreads();
    {
        float acc = bp1[tid];
        #pragma unroll 4
        for (int k = 0; k < MELD; ++k) acc += mel_sh[k] * wp1T[k * P1 + tid];
        hid_sh[tid] = fmaxf(acc, 0.f);
    }
    __syncthreads();
    if (tid < P2) {
        float acc = bp2[tid];
        #pragma unroll 4
        for (int k = 0; k < P1; ++k) acc += hid_sh[k] * wp2T[k * P2 + tid];
        xH[(size_t)bt * P2 + tid] = __float2half(fmaxf(acc, 0.f));
    }
}

// ---------------- 4-block group barrier (agent scope, fence-free) ----------------
__device__ __forceinline__ void groupbar(int* c, int n) {
    __syncthreads();    // drains vmcnt(0): all comm stores visible before RMW
    if (threadIdx.x == 0) {
        __hip_atomic_fetch_add(c, 1, __ATOMIC_RELAXED, __HIP_MEMORY_SCOPE_AGENT);
        while (__hip_atomic_load(c, __ATOMIC_RELAXED, __HIP_MEMORY_SCOPE_AGENT) < 4 * n)
            __builtin_amdgcn_s_sleep(1);
    }
    __syncthreads();
}

// ---------------- decoder ----------------
__global__ __launch_bounds__(1024, 1) void decoder_kernel(const float* __restrict__ bq,
                                                          const float* __restrict__ we,
                                                          const float* __restrict__ bout,
                                                          char* __restrict__ wsb,
                                                          float* __restrict__ out) {
    extern __shared__ __align__(16) char smem[];
    __half* encL     = (__half*)(smem + L_ENC);
    __half* wosL     = (__half*)(smem + L_WOS);
    float*  scr      = (float*)(smem + L_SCR);
    float*  q_sh     = (float*)(smem + L_Q);
    float*  lin_sh   = (float*)(smem + L_LIN);
    float*  en_sh    = (float*)(smem + L_EN);
    float*  gates_sh = (float*)(smem + L_GATE);
    float*  h_sh     = (float*)(smem + L_H);
    float*  c_sh     = (float*)(smem + L_C);
    float*  red_sh   = (float*)(smem + L_RED);

    const int bid  = blockIdx.x;
    const int g    = bid & 63;
    const int m    = bid >> 6;
    const int tid  = threadIdx.x;
    const int lane = tid & 63;
    const int wv   = tid >> 6;

    const __half* encH = (const __half*)(wsb + OFF_ENCH) + (size_t)g * TE * ENC + (size_t)m * 100 * ENC;
    const __half* xH   = (const __half*)(wsb + OFF_XH) + (size_t)g * TMEL * P2;
    const __half* wc   = (const __half*)(wsb + OFF_WCH) + (size_t)m * KCOMB * 256;
    const __half* wqs  = (const __half*)(wsb + OFF_WQS) + (size_t)m * 64 * 512;
    const __half* wos  = (const __half*)(wsb + OFF_WOS) + (size_t)m * 64 * 80;
    const float*  bsq  = (const float*)(wsb + OFF_BSQ) + m * 256;
    char*  comm = wsb + OFF_COMM + (size_t)g * 20480;
    float* qp   = (float*)(comm);            // [4][512]
    float* ctxp = (float*)(comm + 8192);     // [4][512]
    float* ml   = (float*)(comm + 16384);    // [4][2]
    float* hq   = (float*)(comm + 16512);    // [2][256]
    float* melp = (float*)(comm + 18560);    // [4][80]
    int*   barc = (int*)(wsb + OFF_BAR) + g * 64;
    float* outB = out + (size_t)g * TMEL * MELD;

    // ---- one-time LDS staging
    {
        const int4* s1 = (const int4*)encH;
        int4* d1 = (int4*)encL;
        for (int i = tid; i < 6400; i += 1024) d1[i] = s1[i];
        const int4* s2 = (const int4*)wos;
        int4* d2 = (int4*)wosL;
        if (tid < 640) d2[tid] = s2[tid];
    }

    // ---- init: zero comm slots + local state
    if (tid < 512) gstore(&qp[m * 512 + tid], 0.f);
    if (tid < 64) {
        gstore(&hq[m * 64 + tid], 0.f);
        gstore(&hq[256 + m * 64 + tid], 0.f);
        h_sh[tid] = 0.f;
        c_sh[tid] = 0.f;
    }
    groupbar(barc, 1);

    // per-lane energy constants
    float4 wa = ((const float4*)we)[lane * 2];
    float4 wb = ((const float4*)we)[lane * 2 + 1];
    float wsum = wa.x + wa.y + wa.z + wa.w + wb.x + wb.y + wb.z + wb.w;
    wa.x *= 2.f; wa.y *= 2.f; wa.z *= 2.f; wa.w *= 2.f;
    wb.x *= 2.f; wb.y *= 2.f; wb.z *= 2.f; wb.w *= 2.f;

    const float* wq2 = (const float*)wqs;

    // gates-loop addressing: lanes 0-31 take even k, lanes 32-63 odd k,
    // each lane streams one float4 (8 halves = its 8 j-columns) per k-pair.
    const int kb   = wv * 52;
    const int jb   = (lane & 31) * 8;
    const int kpar = lane >> 5;
    const float4* wp4 = (const float4*)(wc + (size_t)(kb + kpar) * 256) + (lane & 31);

    for (int t = 0; t < TMEL; ++t) {
        // early loads for phase B (data committed before prev end-of-step barrier)
        float xv = 0.f, hv = 0.f;
        if (tid < P2) xv = __half2float(xH[(size_t)t * P2 + tid]);
        if (tid >= 512 && tid < 768) hv = gload(&hq[(t & 1) * 256 + (tid - 512)]);

        // ================= phase A =================
        if (m == 0 && t > 0 && tid < MELD) {
            float o = bout[tid] + gload(&melp[tid]) + gload(&melp[80 + tid]) +
                      gload(&melp[160 + tid]) + gload(&melp[240 + tid]);
            outB[(size_t)(t - 1) * MELD + tid] = o;
        }
        if (tid < ENC)
            q_sh[tid] = fmaf(bq[tid], C2F, gload(&qp[tid]) + gload(&qp[512 + tid]) +
                                           gload(&qp[1024 + tid]) + gload(&qp[1536 + tid]));
        __syncthreads();

        // energy for my 100 te rows (enc & q pre-scaled by C2), per-wave max
        {
            float4 qa = ((const float4*)q_sh)[lane * 2];
            float4 qb = ((const float4*)q_sh)[lane * 2 + 1];
            float mx = -1e30f;
            int r = wv;
            float4 raw = ((const float4*)(encL + (size_t)r * ENC))[lane];
            while (r < 100) {
                int rn = r + 16;
                int rc = (rn < 100) ? rn : 0;
                float4 rawn = ((const float4*)(encL + (size_t)rc * ENC))[lane];
                const __half2* hp = (const __half2*)&raw;
                float p = wsum;
                float2 e;
                #define ETERM(qv_, w2v, ev) { float x_ = exp2f((qv_) + (ev)); \
                    float r_ = __builtin_amdgcn_rcpf(x_ + 1.f); \
                    p = fmaf(-(w2v), r_, p); }
                e = __half22float2(hp[0]); ETERM(qa.x, wa.x, e.x); ETERM(qa.y, wa.y, e.y);
                e = __half22float2(hp[1]); ETERM(qa.z, wa.z, e.x); ETERM(qa.w, wa.w, e.y);
                e = __half22float2(hp[2]); ETERM(qb.x, wb.x, e.x); ETERM(qb.y, wb.y, e.y);
                e = __half22float2(hp[3]); ETERM(qb.z, wb.z, e.x); ETERM(qb.w, wb.w, e.y);
                #undef ETERM
                #pragma unroll
                for (int off = 32; off; off >>= 1) p += __shfl_xor(p, off, 64);
                mx = fmaxf(mx, p);
                if (lane == 0) en_sh[r] = p;
                raw = rawn; r = rn;
            }
            if (lane == 0) gates_sh[32 + wv] = mx;   // gates_sh free during phase A
        }
        __syncthreads();
        // exp with inline global max (tid<100 folds the 16 wave maxes)
        if (tid < 100) {
            float M = gates_sh[32];
            #pragma unroll
            for (int w = 1; w < 16; ++w) M = fmaxf(M, gates_sh[32 + w]);
            if (tid == 0) red_sh[0] = M;
            en_sh[tid] = __expf(en_sh[tid] - M);
        }
        __syncthreads();
        // ctx partial + per-wave exp-sum
        {
            float4 a0 = {0.f, 0.f, 0.f, 0.f}, a1 = {0.f, 0.f, 0.f, 0.f};
            float ssum = 0.f;
            int r = wv;
            float4 raw = ((const float4*)(encL + (size_t)r * ENC))[lane];
            while (r < 100) {
                int rn = r + 16;
                int rc = (rn < 100) ? rn : 0;
                float4 rawn = ((const float4*)(encL + (size_t)rc * ENC))[lane];
                float ex = en_sh[r];
                ssum += ex;
                const __half2* hp = (const __half2*)&raw;
                float2 e;
                e = __half22float2(hp[0]); a0.x = fmaf(ex, e.x, a0.x); a0.y = fmaf(ex, e.y, a0.y);
                e = __half22float2(hp[1]); a0.z = fmaf(ex, e.x, a0.z); a0.w = fmaf(ex, e.y, a0.w);
                e = __half22float2(hp[2]); a1.x = fmaf(ex, e.x, a1.x); a1.y = fmaf(ex, e.y, a1.y);
                e = __half22float2(hp[3]); a1.z = fmaf(ex, e.x, a1.z); a1.w = fmaf(ex, e.y, a1.w);
                raw = rawn; r = rn;
            }
            ((float4*)(scr + wv * 512))[lane * 2] = a0;
            ((float4*)(scr + wv * 512))[lane * 2 + 1] = a1;
            if (lane == 0) gates_sh[wv] = ssum;
        }
        __syncthreads();
        if (tid < ENC) {
            float c = 0.f;
            #pragma unroll
            for (int w = 0; w < 16; ++w) c += scr[w * 512 + tid];
            gstore(&ctxp[m * 512 + tid], c);
        }
        if (tid == 0) {
            float S = gates_sh[0];
            #pragma unroll
            for (int w = 1; w < 16; ++w) S += gates_sh[w];
            gstore(&ml[m * 2], red_sh[0]);
            gstore(&ml[m * 2 + 1], S);
        }

        // ---- prefetch gates-weight iters 0..3 before the barrier (step-invariant;
        // latency hides under the barrier drain + spin)
        float4 wbuf[4];
        #pragma unroll
        for (int gg = 0; gg < 4; ++gg) wbuf[gg] = wp4[(size_t)gg * 64];

        groupbar(barc, 2 * t + 2);

        // ================= phase B =================
        float c0 = 0.f, c1 = 0.f, c2 = 0.f, c3 = 0.f;
        if (tid < ENC) {
            c0 = gload(&ctxp[tid]);        c1 = gload(&ctxp[512 + tid]);
            c2 = gload(&ctxp[1024 + tid]); c3 = gload(&ctxp[1536 + tid]);
        }
        if (tid < 8) red_sh[4 + tid] = gload(&ml[tid]);
        __syncthreads();
        float M = fmaxf(fmaxf(red_sh[4], red_sh[6]), fmaxf(red_sh[8], red_sh[10]));
        float s0 = __expf(red_sh[4] - M), s1 = __expf(red_sh[6] - M);
        float s2 = __expf(red_sh[8] - M), s3 = __expf(red_sh[10] - M);
        float linv = __builtin_amdgcn_rcpf(s0 * red_sh[5] + s1 * red_sh[7] +
                                           s2 * red_sh[9] + s3 * red_sh[11]) * INVC2F;
        if (tid < ENC) lin_sh[64 + tid] = (s0 * c0 + s1 * c1 + s2 * c2 + s3 * c3) * linv;
        if (tid < P2) lin_sh[tid] = xv;
        if (tid >= 512 && tid < 768) lin_sh[576 + (tid - 512)] = hv;
        __syncthreads();

        // gates quarter: 16 waves; split-lane dwordx4 stream, distance-4 rotation.
        // Lane covers 8 j (jb..jb+7) for k = kb + 2*gg + kpar, gg = 0..25.
        {
            float a0 = 0.f, a1 = 0.f, a2 = 0.f, a3 = 0.f;
            float a4 = 0.f, a5 = 0.f, a6 = 0.f, a7 = 0.f;
            #pragma unroll
            for (int gg = 0; gg < 26; ++gg) {
                float4 w = wbuf[gg & 3];
                if (gg + 4 < 26) wbuf[gg & 3] = wp4[(size_t)(gg + 4) * 64];
                float s = lin_sh[kb + 2 * gg + kpar];
                const __half2* hp = (const __half2*)&w;
                float2 w01 = __half22float2(hp[0]), w23 = __half22float2(hp[1]);
                float2 w45 = __half22float2(hp[2]), w67 = __half22float2(hp[3]);
                a0 = fmaf(s, w01.x, a0); a1 = fmaf(s, w01.y, a1);
                a2 = fmaf(s, w23.x, a2); a3 = fmaf(s, w23.y, a3);
                a4 = fmaf(s, w45.x, a4); a5 = fmaf(s, w45.y, a5);
                a6 = fmaf(s, w67.x, a6); a7 = fmaf(s, w67.y, a7);
            }
            // combine k-parities: lane l += lane l^32
            a0 += __shfl_xor(a0, 32, 64); a1 += __shfl_xor(a1, 32, 64);
            a2 += __shfl_xor(a2, 32, 64); a3 += __shfl_xor(a3, 32, 64);
            a4 += __shfl_xor(a4, 32, 64); a5 += __shfl_xor(a5, 32, 64);
            a6 += __shfl_xor(a6, 32, 64); a7 += __shfl_xor(a7, 32, 64);
            if (lane < 32) {
                float4 lo = {a0, a1, a2, a3};
                float4 hi = {a4, a5, a6, a7};
                float4* dst = (float4*)(scr + wv * 256 + jb);
                dst[0] = lo;
                dst[1] = hi;
            }
        }

        // prefetch q-projection weights (independent of gates reduce / LSTM)
        float qbuf[2][16];
        if (tid < 256) {
            #pragma unroll
            for (int gg = 0; gg < 2; ++gg) {
                #pragma unroll
                for (int i = 0; i < 16; ++i)
                    qbuf[gg][i] = wq2[(size_t)(16 * gg + i) * 256 + tid];
            }
        }
        __syncthreads();
        if (tid < 256) {
            float gsum = bsq[tid];
            #pragma unroll
            for (int w = 0; w < 16; ++w) gsum += scr[w * 256 + tid];
            gates_sh[tid] = gsum;
        }
        __syncthreads();
        if (tid < 64) {
            float ig = fast_sigmoid(gates_sh[tid]);
            float fg = fast_sigmoid(gates_sh[64 + tid]);
            float gg = fast_tanh(gates_sh[128 + tid]);
            float og = fast_sigmoid(gates_sh[192 + tid]);
            float cN = fmaf(fg, c_sh[tid], ig * gg);
            float hN = og * fast_tanh(cN);
            c_sh[tid] = cN; h_sh[tid] = hN;
            gstore(&hq[((t + 1) & 1) * 256 + m * 64 + tid], hN);
        }
        __syncthreads();
        // q k-partial: 256 threads x j-pairs, rotating 16-wide buffer
        if (tid < 256) {
            float a0 = 0.f, a1 = 0.f;
            #pragma unroll
            for (int gg = 0; gg < 4; ++gg) {
                float rr[16];
                #pragma unroll
                for (int i = 0; i < 16; ++i) rr[i] = qbuf[gg & 1][i];
                if (gg + 2 < 4) {
                    #pragma unroll
                    for (int i = 0; i < 16; ++i)
                        qbuf[gg & 1][i] = wq2[(size_t)(16 * (gg + 2) + i) * 256 + tid];
                }
                #pragma unroll
                for (int i = 0; i < 16; ++i) {
                    __half2 hh = *(const __half2*)&rr[i];
                    float2 w = __half22float2(hh);
                    float h = h_sh[16 * gg + i];
                    a0 = fmaf(h, w.x, a0); a1 = fmaf(h, w.y, a1);
                }
            }
            gstore(&qp[m * 512 + 2 * tid], a0);
            gstore(&qp[m * 512 + 2 * tid + 1], a1);
        }
        // mel k-partial
        if (tid >= 512 && tid < 512 + MELD) {
            int jo = tid - 512;
            float a = 0.f;
            #pragma unroll 8
            for (int kk = 0; kk < 64; ++kk) a = fmaf(h_sh[kk], __half2float(wosL[kk * 80 + jo]), a);
            gstore(&melp[m * 80 + jo], a);
        }
        groupbar(barc, 2 * t + 3);
    }
    // epilogue
    if (m == 0 && tid < MELD) {
        float o = bout[tid] + gload(&melp[tid]) + gload(&melp[80 + tid]) +
                  gload(&melp[160 + tid]) + gload(&melp[240 + tid]);
        outB[(size_t)(TMEL - 1) * MELD + tid] = o;
    }
}

extern "C" void kernel_launch(void* const* d_in, const int* in_sizes, int n_in,
                              void* d_out, int out_size, void* d_ws, size_t ws_size,
                              hipStream_t stream) {
    (void)in_sizes; (void)n_in; (void)out_size; (void)ws_size;
    const float* mel  = (const float*)d_in[0];
    const float* enc  = (const float*)d_in[1];
    const float* Wp1  = (const float*)d_in[2];
    const float* bp1  = (const float*)d_in[3];
    const float* Wp2  = (const float*)d_in[4];
    const float* bp2  = (const float*)d_in[5];
    const float* Wq   = (const float*)d_in[6];
    const float* bq   = (const float*)d_in[7];
    const float* We   = (const float*)d_in[8];
    // d_in[9] = b_e : softmax-invariant constant -> unused
    const float* Wih  = (const float*)d_in[10];
    const float* Whh  = (const float*)d_in[11];
    const float* bih  = (const float*)d_in[12];
    const float* bhh  = (const float*)d_in[13];
    const float* Wout = (const float*)d_in[14];
    const float* bout = (const float*)d_in[15];
    char* wsb  = (char*)d_ws;
    float* out = (float*)d_out;

    long prepBlocks = (PREP_TOT + 255) / 256;
    prep_kernel<<<dim3((unsigned)prepBlocks), 256, 0, stream>>>(
        enc, Wq, Wih, Whh, Wout, Wp1, Wp2, bih, bhh, wsb);
    prenet_kernel<<<NB * TMEL, 128, 0, stream>>>(mel, bp1, bp2, wsb);

    hipFuncSetAttribute((const void*)decoder_kernel,
                        hipFuncAttributeMaxDynamicSharedMemorySize, SMEM_BYTES);

    const float* bq_a = bq; const float* we_a = We; const float* bo_a = bout;
    char* ws_a = wsb; float* out_a = out;
    void* args[] = { &bq_a, &we_a, &bo_a, &ws_a, &out_a };
    hipLaunchCooperativeKernel((const void*)decoder_kernel, dim3(256), dim3(1024),
                               args, SMEM_BYTES, stream);
}